// Round 27
// baseline (364.539 us; speedup 1.0000x reference)
//
#include <hip/hip_runtime.h>
#include <hip/hip_bf16.h>
#include <math.h>

#define N_NODES 100000
#define N_EDGES 800000

typedef float f32x4 __attribute__((ext_vector_type(4)));
typedef short bf16x8 __attribute__((ext_vector_type(8)));

__device__ inline unsigned short bf16_of(float f) {
    union { __hip_bfloat16 b; unsigned short u; } cv;
    cv.b = __float2bfloat16(f);
    return cv.u;
}
__device__ inline float f32_of(unsigned short u) {
    union { __hip_bfloat16 b; unsigned short u; } cv;
    cv.u = u;
    return __bfloat162float(cv.b);
}

// ================= degree / CSR build =================
__global__ void k_zero_deg(int* __restrict__ deg) {
    int i = blockIdx.x * blockDim.x + threadIdx.x;
    if (i < N_NODES) deg[i] = 0;
}

__global__ void k_hist(const int* __restrict__ edst, int* __restrict__ deg) {
    int e = blockIdx.x * blockDim.x + threadIdx.x;
    if (e < N_EDGES) atomicAdd(&deg[edst[e]], 1);
}

// exclusive scan + dinv fused, 256/block
__global__ void k_scan1(const int* __restrict__ deg, int* __restrict__ off,
                        int* __restrict__ bsum, float* __restrict__ dinv, int n) {
    __shared__ int s[256];
    int t = threadIdx.x;
    int i = blockIdx.x * 256 + t;
    int v = (i < n) ? deg[i] : 0;
    if (i < n) dinv[i] = rsqrtf((float)(v + 1));   // +1 self-loop
    s[t] = v;
    __syncthreads();
    #pragma unroll
    for (int d = 1; d < 256; d <<= 1) {
        int x = (t >= d) ? s[t - d] : 0;
        __syncthreads();
        s[t] += x;
        __syncthreads();
    }
    if (i < n) off[i] = s[t] - v;            // exclusive within block
    if (t == 255) bsum[blockIdx.x] = s[255];
}

__global__ void k_scan2(int* __restrict__ bsum, int nb) {
    __shared__ int s[512];
    int t = threadIdx.x;
    int v = (t < nb) ? bsum[t] : 0;
    s[t] = v;
    __syncthreads();
    #pragma unroll
    for (int d = 1; d < 512; d <<= 1) {
        int x = (t >= d) ? s[t - d] : 0;
        __syncthreads();
        s[t] += x;
        __syncthreads();
    }
    if (t < nb) bsum[t] = s[t] - v;          // exclusive block offsets
}

__global__ void k_scan3(int* __restrict__ off, const int* __restrict__ bsum,
                        int* __restrict__ cur, int n) {
    int i = blockIdx.x * blockDim.x + threadIdx.x;
    if (i < n) {
        int o = off[i] + bsum[i >> 8];
        off[i] = o;
        cur[i] = o;
    }
    if (i == n) off[n] = N_EDGES;
}

// scatter edges into dst-grouped CSR: ONE packed int4 {src, dst, w_bits, eid} per edge
__global__ void k_scatter(const int* __restrict__ esrc, const int* __restrict__ edst,
                          const float* __restrict__ dinv,
                          int* __restrict__ cur, int4* __restrict__ csr_pack) {
    int e = blockIdx.x * blockDim.x + threadIdx.x;
    if (e >= N_EDGES) return;
    int s = esrc[e], d = edst[e];
    int pos = atomicAdd(&cur[d], 1);
    float w = dinv[s] * dinv[d];
    csr_pack[pos] = make_int4(s, d, __float_as_int(w), e);
}

// ================= block-local degree sort (divergence fix, atomic-free) ===============
// One 128-thread block bitonic-sorts its 128-node tile by (deg, node) in LDS.
// perm[tile*128 + rank] = node. Deterministic (node tiebreak); sentinels sort last.
__global__ __launch_bounds__(128) void k_tile_sort(const int* __restrict__ deg,
                                                   int* __restrict__ perm, int n) {
    __shared__ unsigned long long sk[128];
    const int t = threadIdx.x;
    const int base = blockIdx.x * 128;
    const int node = base + t;
    unsigned long long key;
    if (node < n)
        key = ((unsigned long long)(unsigned int)deg[node] << 32) | (unsigned int)node;
    else
        key = 0xFFFFFFFFFFFFFFFFull;
    sk[t] = key;
    __syncthreads();
    #pragma unroll
    for (int k = 2; k <= 128; k <<= 1) {
        #pragma unroll
        for (int j = k >> 1; j > 0; j >>= 1) {
            int ixj = t ^ j;
            if (ixj > t) {
                unsigned long long a = sk[t], b = sk[ixj];
                bool up = ((t & k) == 0);
                if ((a > b) == up) { sk[t] = b; sk[ixj] = a; }
            }
            __syncthreads();
        }
    }
    if (node < n) perm[node] = (int)(sk[t] & 0xFFFFFFFFu);
}

// ================= bf16 hi/lo split of 5 x (128x128) W into MFMA fragment layout ====
// frag index for (k, c): lane = ((k>>3)&3)*16 + (c&15), elem = k&7, tile = (k>>5)*8 + (c>>4)
struct SplitArgs {
    const float* W[5];
    unsigned short* Wh[5];
    unsigned short* Wl[5];
};
__global__ void k_split_all(SplitArgs a) {
    int which = blockIdx.x >> 6;                    // 64 blocks per matrix
    int idx = (blockIdx.x & 63) * 256 + threadIdx.x;
    if (idx >= 128 * 128) return;
    int k = idx >> 7, c = idx & 127;
    float wv = a.W[which][idx];
    unsigned short h = bf16_of(wv);
    unsigned short lo = bf16_of(wv - f32_of(h));
    int fi = (((k >> 5) * 8 + (c >> 4)) * 64 + (((k >> 3) & 3) * 16 + (c & 15))) * 8 + (k & 7);
    a.Wh[which][fi] = h;
    a.Wl[which][fi] = lo;
}

// ================= MFMA node GEMM (f32 input, 3-term): out_bf16 = in @ W ==============
__global__ __launch_bounds__(512) void k_gemm_mfma_f32(
    const float* __restrict__ in,
    const unsigned short* __restrict__ Whf, const unsigned short* __restrict__ Wlf,
    unsigned short* __restrict__ outp, int nrows, int rtiles)
{
    __shared__ __align__(16) unsigned short sWh[16384];
    __shared__ __align__(16) unsigned short sWl[16384];
    const int t = threadIdx.x;

    #pragma unroll
    for (int i = 0; i < 4; ++i) {
        ((float4*)sWh)[t + 512 * i] = ((const float4*)Whf)[t + 512 * i];
        ((float4*)sWl)[t + 512 * i] = ((const float4*)Wlf)[t + 512 * i];
    }
    __syncthreads();

    const int w = t >> 6, l = t & 63;
    const int lr = l & 15, lk = l >> 4;

    for (int r = 0; r < rtiles; ++r) {
        const int row0 = (blockIdx.x * rtiles + r) * 128;
        int arow = row0 + w * 16 + lr;
        if (arow >= nrows) arow = nrows - 1;
        const float* inrow = in + (size_t)arow * 128 + lk * 8;

        bf16x8 ah[4], al[4];
        #pragma unroll
        for (int ks = 0; ks < 4; ++ks) {
            float4 p0 = *(const float4*)(inrow + ks * 32);
            float4 p1 = *(const float4*)(inrow + ks * 32 + 4);
            float z[8] = {p0.x, p0.y, p0.z, p0.w, p1.x, p1.y, p1.z, p1.w};
            #pragma unroll
            for (int e = 0; e < 8; ++e) {
                unsigned short hu = bf16_of(z[e]);
                ah[ks][e] = (short)hu;
                al[ks][e] = (short)bf16_of(z[e] - f32_of(hu));
            }
        }

        f32x4 acc[8];
        #pragma unroll
        for (int ct = 0; ct < 8; ++ct) { f32x4 zz = {0.f, 0.f, 0.f, 0.f}; acc[ct] = zz; }

        #pragma unroll
        for (int ct = 0; ct < 8; ++ct) {
            #pragma unroll
            for (int ks = 0; ks < 4; ++ks) {
                const bf16x8 bh = *(const bf16x8*)(sWh + ((ks * 8 + ct) * 64 + l) * 8);
                const bf16x8 bl = *(const bf16x8*)(sWl + ((ks * 8 + ct) * 64 + l) * 8);
                acc[ct] = __builtin_amdgcn_mfma_f32_16x16x32_bf16(ah[ks], bh, acc[ct], 0, 0, 0);
                acc[ct] = __builtin_amdgcn_mfma_f32_16x16x32_bf16(ah[ks], bl, acc[ct], 0, 0, 0);
                acc[ct] = __builtin_amdgcn_mfma_f32_16x16x32_bf16(al[ks], bh, acc[ct], 0, 0, 0);
            }
        }

        #pragma unroll
        for (int j = 0; j < 4; ++j) {
            int m = row0 + w * 16 + lk * 4 + j;
            if (m < nrows) {
                #pragma unroll
                for (int ct = 0; ct < 8; ++ct)
                    outp[(size_t)m * 128 + ct * 16 + lr] = bf16_of(acc[ct][j]);
            }
        }
    }
}

// ===== shared agg helper pattern (ILP-4): 4 lanes of a row load 4 records at once,
// shfl-broadcast within the 16-stride lane group, then 4 independent row gathers.
// Rows processed in tile-local degree-sorted perm order -> waves have uniform loops. =====

// ================= FUSED agg + GEMM: out = bf16( relu(bias + norm-agg(raw)) @ W ) ======
__global__ __launch_bounds__(512) void k_fused_agg_gemm(
    const unsigned short* __restrict__ raw, const float* __restrict__ dinv,
    const int* __restrict__ off, const int4* __restrict__ csr_pack,
    const int* __restrict__ perm, const float* __restrict__ bias,
    const unsigned short* __restrict__ Whf, const unsigned short* __restrict__ Wlf,
    unsigned short* __restrict__ outp, int nrows)
{
    __shared__ __align__(16) unsigned short sWh[16384];
    __shared__ __align__(16) unsigned short sWl[16384];
    const int t = threadIdx.x;

    // issue weight staging first; agg gathers below overlap its latency
    #pragma unroll
    for (int i = 0; i < 4; ++i) {
        ((float4*)sWh)[t + 512 * i] = ((const float4*)Whf)[t + 512 * i];
        ((float4*)sWl)[t + 512 * i] = ((const float4*)Wlf)[t + 512 * i];
    }

    const int w = t >> 6, l = t & 63;
    const int lr = l & 15, lk = l >> 4;
    const int row0 = blockIdx.x * 128;
    int ppos = row0 + w * 16 + lr;
    if (ppos >= nrows) ppos = nrows - 1;
    const int arow = perm[ppos];

    const unsigned short* self = raw + (size_t)arow * 128 + lk * 8;
    const float* brow = bias + lk * 8;
    float di = dinv[arow];
    float w0 = di * di;

    float facc[4][8];
    #pragma unroll
    for (int ks = 0; ks < 4; ++ks) {
        bf16x8 v = *(const bf16x8*)(self + ks * 32);
        float4 b0 = *(const float4*)(brow + ks * 32);
        float4 b1v = *(const float4*)(brow + ks * 32 + 4);
        float bb[8] = {b0.x, b0.y, b0.z, b0.w, b1v.x, b1v.y, b1v.z, b1v.w};
        #pragma unroll
        for (int e = 0; e < 8; ++e)
            facc[ks][e] = bb[e] + w0 * f32_of((unsigned short)v[e]);
    }

    const int beg = off[arow], end = off[arow + 1];
    for (int j = beg; j < end; j += 4) {
        int4 p = make_int4(0, 0, 0, 0);
        if (j + lk < end) p = csr_pack[j + lk];     // 4 records, one per lane
        #pragma unroll
        for (int k = 0; k < 4; ++k) {
            if (j + k < end) {                       // row-uniform predicate
                int si = __shfl(p.x, lr + 16 * k, 64);
                float wg = __int_as_float(__shfl(p.z, lr + 16 * k, 64));
                const unsigned short* nrow = raw + (size_t)si * 128 + lk * 8;
                #pragma unroll
                for (int ks = 0; ks < 4; ++ks) {
                    bf16x8 u = *(const bf16x8*)(nrow + ks * 32);
                    #pragma unroll
                    for (int e = 0; e < 8; ++e)
                        facc[ks][e] += wg * f32_of((unsigned short)u[e]);
                }
            }
        }
    }

    bf16x8 ah[4];
    #pragma unroll
    for (int ks = 0; ks < 4; ++ks)
        #pragma unroll
        for (int e = 0; e < 8; ++e)
            ah[ks][e] = (short)bf16_of(fmaxf(facc[ks][e], 0.f));

    __syncthreads();                                 // weights staged

    f32x4 acc[8];
    #pragma unroll
    for (int ct = 0; ct < 8; ++ct) { f32x4 zz = {0.f, 0.f, 0.f, 0.f}; acc[ct] = zz; }
    #pragma unroll
    for (int ct = 0; ct < 8; ++ct) {
        #pragma unroll
        for (int ks = 0; ks < 4; ++ks) {
            const bf16x8 bh = *(const bf16x8*)(sWh + ((ks * 8 + ct) * 64 + l) * 8);
            const bf16x8 bl = *(const bf16x8*)(sWl + ((ks * 8 + ct) * 64 + l) * 8);
            acc[ct] = __builtin_amdgcn_mfma_f32_16x16x32_bf16(ah[ks], bh, acc[ct], 0, 0, 0);
            acc[ct] = __builtin_amdgcn_mfma_f32_16x16x32_bf16(ah[ks], bl, acc[ct], 0, 0, 0);
        }
    }

    #pragma unroll
    for (int j = 0; j < 4; ++j) {
        int mpos = row0 + w * 16 + lk * 4 + j;
        if (mpos < nrows) {
            int mnode = perm[mpos];                  // L2-hot
            #pragma unroll
            for (int ct = 0; ct < 8; ++ct)
                outp[(size_t)mnode * 128 + ct * 16 + lr] = bf16_of(acc[ct][j]);
        }
    }
}

// ================= FUSED agg + P/Q GEMMs: z=relu(bias+agg); P=z@Wa + bm1; Q=z@Wb =======
__global__ __launch_bounds__(512) void k_fused_agg_pq(
    const unsigned short* __restrict__ raw, const float* __restrict__ dinv,
    const int* __restrict__ off, const int4* __restrict__ csr_pack,
    const int* __restrict__ perm,
    const float* __restrict__ bias, const float* __restrict__ bm1,
    const unsigned short* __restrict__ Wh0, const unsigned short* __restrict__ Wl0,
    const unsigned short* __restrict__ Wh1, const unsigned short* __restrict__ Wl1,
    unsigned short* __restrict__ P, unsigned short* __restrict__ Q, int nrows)
{
    __shared__ __align__(16) unsigned short sWh[16384];
    __shared__ __align__(16) unsigned short sWl[16384];
    const int t = threadIdx.x;

    #pragma unroll
    for (int i = 0; i < 4; ++i) {
        ((float4*)sWh)[t + 512 * i] = ((const float4*)Wh0)[t + 512 * i];
        ((float4*)sWl)[t + 512 * i] = ((const float4*)Wl0)[t + 512 * i];
    }

    const int w = t >> 6, l = t & 63;
    const int lr = l & 15, lk = l >> 4;
    const int row0 = blockIdx.x * 128;
    int ppos = row0 + w * 16 + lr;
    if (ppos >= nrows) ppos = nrows - 1;
    const int arow = perm[ppos];

    const unsigned short* self = raw + (size_t)arow * 128 + lk * 8;
    const float* brow = bias + lk * 8;
    float di = dinv[arow];
    float w0 = di * di;

    float facc[4][8];
    #pragma unroll
    for (int ks = 0; ks < 4; ++ks) {
        bf16x8 v = *(const bf16x8*)(self + ks * 32);
        float4 b0 = *(const float4*)(brow + ks * 32);
        float4 b1v = *(const float4*)(brow + ks * 32 + 4);
        float bb[8] = {b0.x, b0.y, b0.z, b0.w, b1v.x, b1v.y, b1v.z, b1v.w};
        #pragma unroll
        for (int e = 0; e < 8; ++e)
            facc[ks][e] = bb[e] + w0 * f32_of((unsigned short)v[e]);
    }

    const int beg = off[arow], end = off[arow + 1];
    for (int j = beg; j < end; j += 4) {
        int4 p = make_int4(0, 0, 0, 0);
        if (j + lk < end) p = csr_pack[j + lk];
        #pragma unroll
        for (int k = 0; k < 4; ++k) {
            if (j + k < end) {
                int si = __shfl(p.x, lr + 16 * k, 64);
                float wg = __int_as_float(__shfl(p.z, lr + 16 * k, 64));
                const unsigned short* nrow = raw + (size_t)si * 128 + lk * 8;
                #pragma unroll
                for (int ks = 0; ks < 4; ++ks) {
                    bf16x8 u = *(const bf16x8*)(nrow + ks * 32);
                    #pragma unroll
                    for (int e = 0; e < 8; ++e)
                        facc[ks][e] += wg * f32_of((unsigned short)u[e]);
                }
            }
        }
    }

    bf16x8 ah[4];
    #pragma unroll
    for (int ks = 0; ks < 4; ++ks)
        #pragma unroll
        for (int e = 0; e < 8; ++e)
            ah[ks][e] = (short)bf16_of(fmaxf(facc[ks][e], 0.f));

    // bm1 folded into P: bmv[ct] = bm1[ct*16+lr]
    float bmv[8];
    #pragma unroll
    for (int ct = 0; ct < 8; ++ct) bmv[ct] = bm1[ct * 16 + lr];

    __syncthreads();                                 // W0 staged

    {
        f32x4 acc[8];
        #pragma unroll
        for (int ct = 0; ct < 8; ++ct) { f32x4 zz = {0.f, 0.f, 0.f, 0.f}; acc[ct] = zz; }
        #pragma unroll
        for (int ct = 0; ct < 8; ++ct) {
            #pragma unroll
            for (int ks = 0; ks < 4; ++ks) {
                const bf16x8 bh = *(const bf16x8*)(sWh + ((ks * 8 + ct) * 64 + l) * 8);
                const bf16x8 bl = *(const bf16x8*)(sWl + ((ks * 8 + ct) * 64 + l) * 8);
                acc[ct] = __builtin_amdgcn_mfma_f32_16x16x32_bf16(ah[ks], bh, acc[ct], 0, 0, 0);
                acc[ct] = __builtin_amdgcn_mfma_f32_16x16x32_bf16(ah[ks], bl, acc[ct], 0, 0, 0);
            }
        }
        #pragma unroll
        for (int j = 0; j < 4; ++j) {
            int mpos = row0 + w * 16 + lk * 4 + j;
            if (mpos < nrows) {
                int mnode = perm[mpos];
                #pragma unroll
                for (int ct = 0; ct < 8; ++ct)
                    P[(size_t)mnode * 128 + ct * 16 + lr] = bf16_of(acc[ct][j] + bmv[ct]);
            }
        }
    }

    __syncthreads();                                 // all reads of W0 done
    #pragma unroll
    for (int i = 0; i < 4; ++i) {
        ((float4*)sWh)[t + 512 * i] = ((const float4*)Wh1)[t + 512 * i];
        ((float4*)sWl)[t + 512 * i] = ((const float4*)Wl1)[t + 512 * i];
    }
    __syncthreads();                                 // W1 staged

    {
        f32x4 acc[8];
        #pragma unroll
        for (int ct = 0; ct < 8; ++ct) { f32x4 zz = {0.f, 0.f, 0.f, 0.f}; acc[ct] = zz; }
        #pragma unroll
        for (int ct = 0; ct < 8; ++ct) {
            #pragma unroll
            for (int ks = 0; ks < 4; ++ks) {
                const bf16x8 bh = *(const bf16x8*)(sWh + ((ks * 8 + ct) * 64 + l) * 8);
                const bf16x8 bl = *(const bf16x8*)(sWl + ((ks * 8 + ct) * 64 + l) * 8);
                acc[ct] = __builtin_amdgcn_mfma_f32_16x16x32_bf16(ah[ks], bh, acc[ct], 0, 0, 0);
                acc[ct] = __builtin_amdgcn_mfma_f32_16x16x32_bf16(ah[ks], bl, acc[ct], 0, 0, 0);
            }
        }
        #pragma unroll
        for (int j = 0; j < 4; ++j) {
            int mpos = row0 + w * 16 + lk * 4 + j;
            if (mpos < nrows) {
                int mnode = perm[mpos];
                #pragma unroll
                for (int ct = 0; ct < 8; ++ct)
                    Q[(size_t)mnode * 128 + ct * 16 + lr] = bf16_of(acc[ct][j]);
            }
        }
    }
}

// ================= fused edge MLP (MFMA 2-term, CSR order, phase-split weights) ========
// bm1 already folded into P -> z1 = relu(P[s] + Q[d]).
__global__ __launch_bounds__(512) void k_edge_mlp_mfma(
    const int4* __restrict__ csr_pack,
    const unsigned short* __restrict__ P, const unsigned short* __restrict__ Q,
    const unsigned short* __restrict__ Whf, const unsigned short* __restrict__ Wlf,
    const float* __restrict__ bm2,
    const float* __restrict__ Wm3, const float* __restrict__ bm3,
    float* __restrict__ outp)
{
    __shared__ __align__(16) unsigned short sW[16384];   // 32 KB: [0,8192)=h, [8192,16384)=l
    __shared__ int sIdx[3][128];

    const int t = threadIdx.x;
    const int e0 = blockIdx.x * 128;

    if (t < 128) {
        int4 p = csr_pack[e0 + t];
        sIdx[0][t] = p.x;
        sIdx[1][t] = p.y;
        sIdx[2][t] = p.w;
    }
    __syncthreads();

    const int w = t >> 6;          // wave id 0..7: rows w*16 .. w*16+15
    const int l = t & 63;
    const int lr = l & 15;         // A row within tile / D col
    const int lk = l >> 4;         // k-block
    const int row = w * 16 + lr;
    const int s = sIdx[0][row], d = sIdx[1][row];
    const unsigned short* prow = P + (size_t)s * 128 + lk * 8;
    const unsigned short* qrow = Q + (size_t)d * 128 + lk * 8;

    bf16x8 ah[4];
    #pragma unroll
    for (int ks = 0; ks < 4; ++ks) {
        bf16x8 pv = *(const bf16x8*)(prow + ks * 32);
        bf16x8 qv = *(const bf16x8*)(qrow + ks * 32);
        #pragma unroll
        for (int e = 0; e < 8; ++e) {
            float zv = fmaxf(f32_of((unsigned short)pv[e]) +
                             f32_of((unsigned short)qv[e]), 0.f);
            ah[ks][e] = (short)bf16_of(zv);
        }
    }

    f32x4 acc[8];
    #pragma unroll
    for (int ct = 0; ct < 8; ++ct) {
        float bv = bm2[ct * 16 + lr];
        f32x4 a = {bv, bv, bv, bv};
        acc[ct] = a;
    }

    // two phases: ct in [0,4) then [4,8); each stages 16 h-tiles + 16 l-tiles (32 KB)
    #pragma unroll
    for (int ph = 0; ph < 2; ++ph) {
        if (ph) __syncthreads();
        #pragma unroll
        for (int i = 0; i < 2; ++i) {
            int li = t + 512 * i;
            int tl = li >> 6, off = li & 63;
            int gtile = (tl >> 2) * 8 + ph * 4 + (tl & 3);
            ((float4*)sW)[li] = ((const float4*)Whf)[gtile * 64 + off];
            ((float4*)(sW + 8192))[li] = ((const float4*)Wlf)[gtile * 64 + off];
        }
        __syncthreads();
        #pragma unroll
        for (int ct4 = 0; ct4 < 4; ++ct4) {
            int ct = ph * 4 + ct4;
            #pragma unroll
            for (int ks = 0; ks < 4; ++ks) {
                int tl = ks * 4 + ct4;
                const bf16x8 bh = *(const bf16x8*)(sW + (tl * 64 + l) * 8);
                const bf16x8 bl = *(const bf16x8*)(sW + 8192 + (tl * 64 + l) * 8);
                acc[ct] = __builtin_amdgcn_mfma_f32_16x16x32_bf16(ah[ks], bh, acc[ct], 0, 0, 0);
                acc[ct] = __builtin_amdgcn_mfma_f32_16x16x32_bf16(ah[ks], bl, acc[ct], 0, 0, 0);
            }
        }
    }

    float w3v[8];
    #pragma unroll
    for (int ct = 0; ct < 8; ++ct) w3v[ct] = Wm3[ct * 16 + lr];
    float b3 = bm3[0];
    #pragma unroll
    for (int j = 0; j < 4; ++j) {
        float pj = 0.f;
        #pragma unroll
        for (int ct = 0; ct < 8; ++ct) pj += fmaxf(acc[ct][j], 0.f) * w3v[ct];
        pj += __shfl_xor(pj, 1);
        pj += __shfl_xor(pj, 2);
        pj += __shfl_xor(pj, 4);
        pj += __shfl_xor(pj, 8);
        if (lr == 0)
            outp[sIdx[2][w * 16 + lk * 4 + j]] = 1.f / (1.f + expf(-(pj + b3)));
    }
}

// ================= launch =================
extern "C" void kernel_launch(void* const* d_in, const int* in_sizes, int n_in,
                              void* d_out, int out_size, void* d_ws, size_t ws_size,
                              hipStream_t stream) {
    const float* x   = (const float*)d_in[0];
    const int*   ei  = (const int*)d_in[1];
    const float* W1  = (const float*)d_in[2];
    const float* b1  = (const float*)d_in[3];
    const float* W2  = (const float*)d_in[4];
    const float* b2  = (const float*)d_in[5];
    const float* Wm1 = (const float*)d_in[6];
    const float* bm1 = (const float*)d_in[7];
    const float* Wm2 = (const float*)d_in[8];
    const float* bm2 = (const float*)d_in[9];
    const float* Wm3 = (const float*)d_in[10];
    const float* bm3 = (const float*)d_in[11];
    const int* esrc = ei;
    const int* edst = ei + N_EDGES;
    float* outp = (float*)d_out;

    // workspace layout
    float* ws = (float*)d_ws;
    float* dinv = ws;                                   // 100096 floats
    float* A = ws + 100096;                             // N*128 f32 region
    float* B = A + (size_t)N_NODES * 128;               // N*128 f32 region
    int* deg     = (int*)(B + (size_t)N_NODES * 128);   // N
    int* off     = deg + N_NODES;                       // N+1
    int* cur     = off + N_NODES + 1;                   // N
    int* bsum    = cur + N_NODES;                       // 512
    int* perm    = bsum + 512;                          // N
    // align to 16 B for int4
    size_t ioff = (size_t)(perm + N_NODES - (int*)d_ws);
    ioff = (ioff + 3) & ~(size_t)3;
    int4* csr_pack = (int4*)((int*)d_ws + ioff);        // E int4
    unsigned short* frag = (unsigned short*)(csr_pack + N_EDGES);
    unsigned short* W1h   = frag;                 unsigned short* W1l   = frag + 16384;
    unsigned short* W2h   = frag + 2 * 16384;     unsigned short* W2l   = frag + 3 * 16384;
    unsigned short* Wm1ah = frag + 4 * 16384;     unsigned short* Wm1al = frag + 5 * 16384;
    unsigned short* Wm1bh = frag + 6 * 16384;     unsigned short* Wm1bl = frag + 7 * 16384;
    unsigned short* Wm2h  = frag + 8 * 16384;     unsigned short* Wm2l  = frag + 9 * 16384;
    // bf16 views: Ab = layer-1 product (region A); Cb = layer-2 product (region B);
    // Pb overwrites Ab (dead once fused_pq reads only Cb); Qb after Pb in region A.
    unsigned short* Ab = (unsigned short*)A;
    unsigned short* Cb = (unsigned short*)B;
    unsigned short* Pb = (unsigned short*)A;
    unsigned short* Qb = (unsigned short*)A + (size_t)N_NODES * 128;

    const int nb = (N_NODES + 255) / 256;               // 391 scan blocks
    const int node_tiles = (N_NODES + 127) / 128;       // 782

    // ---- CSR build + tile-local degree sort + W splits ----
    k_zero_deg<<<nb, 256, 0, stream>>>(deg);
    k_hist<<<(N_EDGES + 255) / 256, 256, 0, stream>>>(edst, deg);
    k_scan1<<<nb, 256, 0, stream>>>(deg, off, bsum, dinv, N_NODES);
    k_scan2<<<1, 512, 0, stream>>>(bsum, nb);
    k_scan3<<<(N_NODES + 256) / 256, 256, 0, stream>>>(off, bsum, cur, N_NODES);
    k_scatter<<<(N_EDGES + 255) / 256, 256, 0, stream>>>(esrc, edst, dinv, cur, csr_pack);
    k_tile_sort<<<node_tiles, 128, 0, stream>>>(deg, perm, N_NODES);

    SplitArgs sa;
    sa.W[0] = W1;  sa.Wh[0] = W1h;   sa.Wl[0] = W1l;
    sa.W[1] = W2;  sa.Wh[1] = W2h;   sa.Wl[1] = W2l;
    sa.W[2] = Wm1; sa.Wh[2] = Wm1ah; sa.Wl[2] = Wm1al;
    sa.W[3] = Wm1 + 128 * 128; sa.Wh[3] = Wm1bh; sa.Wl[3] = Wm1bl;
    sa.W[4] = Wm2; sa.Wh[4] = Wm2h;  sa.Wl[4] = Wm2l;
    k_split_all<<<5 * 64, 256, 0, stream>>>(sa);

    const int RT = 4;
    const int gemm_blocks = (N_NODES + 128 * RT - 1) / (128 * RT);   // 196

    // ---- layer 1 product: Ab = bf16(x @ W1) ----
    k_gemm_mfma_f32<<<gemm_blocks, 512, 0, stream>>>(x, W1h, W1l, Ab, N_NODES, RT);

    // ---- fused: Cb = bf16( relu(b1 + agg(Ab)) @ W2 ), tile-sorted rows ----
    k_fused_agg_gemm<<<node_tiles, 512, 0, stream>>>(Ab, dinv, off, csr_pack, perm, b1,
                                                     W2h, W2l, Cb, N_NODES);

    // ---- fused: z2 = relu(b2 + agg(Cb)); Pb = z2@Wm1_top + bm1; Qb = z2@Wm1_bot ----
    k_fused_agg_pq<<<node_tiles, 512, 0, stream>>>(Cb, dinv, off, csr_pack, perm, b2, bm1,
                                                   Wm1ah, Wm1al, Wm1bh, Wm1bl,
                                                   Pb, Qb, N_NODES);

    // ---- fused edge MLP on MFMA, CSR order, phase-split weight LDS ----
    k_edge_mlp_mfma<<<N_EDGES / 128, 512, 0, stream>>>(csr_pack, Pb, Qb,
                                                       Wm2h, Wm2l, bm2, Wm3, bm3, outp);
}

// Round 28
// 349.102 us; speedup vs baseline: 1.0442x; 1.0442x over previous
//
#include <hip/hip_runtime.h>
#include <hip/hip_bf16.h>
#include <math.h>

#define N_NODES 100000
#define N_EDGES 800000

typedef float f32x4 __attribute__((ext_vector_type(4)));
typedef short bf16x8 __attribute__((ext_vector_type(8)));

__device__ inline unsigned short bf16_of(float f) {
    union { __hip_bfloat16 b; unsigned short u; } cv;
    cv.b = __float2bfloat16(f);
    return cv.u;
}
__device__ inline float f32_of(unsigned short u) {
    union { __hip_bfloat16 b; unsigned short u; } cv;
    cv.u = u;
    return __bfloat162float(cv.b);
}

// ================= degree / CSR build =================
__global__ void k_zero_deg(int* __restrict__ deg) {
    int i = blockIdx.x * blockDim.x + threadIdx.x;
    if (i < N_NODES) deg[i] = 0;
}

__global__ void k_hist(const int* __restrict__ edst, int* __restrict__ deg) {
    int e = blockIdx.x * blockDim.x + threadIdx.x;
    if (e < N_EDGES) atomicAdd(&deg[edst[e]], 1);
}

// exclusive scan + dinv fused, 256/block
__global__ void k_scan1(const int* __restrict__ deg, int* __restrict__ off,
                        int* __restrict__ bsum, float* __restrict__ dinv, int n) {
    __shared__ int s[256];
    int t = threadIdx.x;
    int i = blockIdx.x * 256 + t;
    int v = (i < n) ? deg[i] : 0;
    if (i < n) dinv[i] = rsqrtf((float)(v + 1));   // +1 self-loop
    s[t] = v;
    __syncthreads();
    #pragma unroll
    for (int d = 1; d < 256; d <<= 1) {
        int x = (t >= d) ? s[t - d] : 0;
        __syncthreads();
        s[t] += x;
        __syncthreads();
    }
    if (i < n) off[i] = s[t] - v;            // exclusive within block
    if (t == 255) bsum[blockIdx.x] = s[255];
}

__global__ void k_scan2(int* __restrict__ bsum, int nb) {
    __shared__ int s[512];
    int t = threadIdx.x;
    int v = (t < nb) ? bsum[t] : 0;
    s[t] = v;
    __syncthreads();
    #pragma unroll
    for (int d = 1; d < 512; d <<= 1) {
        int x = (t >= d) ? s[t - d] : 0;
        __syncthreads();
        s[t] += x;
        __syncthreads();
    }
    if (t < nb) bsum[t] = s[t] - v;          // exclusive block offsets
}

__global__ void k_scan3(int* __restrict__ off, const int* __restrict__ bsum,
                        int* __restrict__ cur, int n) {
    int i = blockIdx.x * blockDim.x + threadIdx.x;
    if (i < n) {
        int o = off[i] + bsum[i >> 8];
        off[i] = o;
        cur[i] = o;
    }
    if (i == n) off[n] = N_EDGES;
}

// scatter edges into dst-grouped CSR: ONE packed int4 {src, dst, w_bits, eid} per edge
__global__ void k_scatter(const int* __restrict__ esrc, const int* __restrict__ edst,
                          const float* __restrict__ dinv,
                          int* __restrict__ cur, int4* __restrict__ csr_pack) {
    int e = blockIdx.x * blockDim.x + threadIdx.x;
    if (e >= N_EDGES) return;
    int s = esrc[e], d = edst[e];
    int pos = atomicAdd(&cur[d], 1);
    float w = dinv[s] * dinv[d];
    csr_pack[pos] = make_int4(s, d, __float_as_int(w), e);
}

// ================= bf16 hi/lo split of 5 x (128x128) W into MFMA fragment layout ====
// frag index for (k, c): lane = ((k>>3)&3)*16 + (c&15), elem = k&7, tile = (k>>5)*8 + (c>>4)
struct SplitArgs {
    const float* W[5];
    unsigned short* Wh[5];
    unsigned short* Wl[5];
};
__global__ void k_split_all(SplitArgs a) {
    int which = blockIdx.x >> 6;                    // 64 blocks per matrix
    int idx = (blockIdx.x & 63) * 256 + threadIdx.x;
    if (idx >= 128 * 128) return;
    int k = idx >> 7, c = idx & 127;
    float wv = a.W[which][idx];
    unsigned short h = bf16_of(wv);
    unsigned short lo = bf16_of(wv - f32_of(h));
    int fi = (((k >> 5) * 8 + (c >> 4)) * 64 + (((k >> 3) & 3) * 16 + (c & 15))) * 8 + (k & 7);
    a.Wh[which][fi] = h;
    a.Wl[which][fi] = lo;
}

// ================= MFMA node GEMM (f32 input, 3-term): out_bf16 = in @ W ==============
__global__ __launch_bounds__(512) void k_gemm_mfma_f32(
    const float* __restrict__ in,
    const unsigned short* __restrict__ Whf, const unsigned short* __restrict__ Wlf,
    unsigned short* __restrict__ outp, int nrows, int rtiles)
{
    __shared__ __align__(16) unsigned short sWh[16384];
    __shared__ __align__(16) unsigned short sWl[16384];
    const int t = threadIdx.x;

    #pragma unroll
    for (int i = 0; i < 4; ++i) {
        ((float4*)sWh)[t + 512 * i] = ((const float4*)Whf)[t + 512 * i];
        ((float4*)sWl)[t + 512 * i] = ((const float4*)Wlf)[t + 512 * i];
    }
    __syncthreads();

    const int w = t >> 6, l = t & 63;
    const int lr = l & 15, lk = l >> 4;

    for (int r = 0; r < rtiles; ++r) {
        const int row0 = (blockIdx.x * rtiles + r) * 128;
        int arow = row0 + w * 16 + lr;
        if (arow >= nrows) arow = nrows - 1;
        const float* inrow = in + (size_t)arow * 128 + lk * 8;

        bf16x8 ah[4], al[4];
        #pragma unroll
        for (int ks = 0; ks < 4; ++ks) {
            float4 p0 = *(const float4*)(inrow + ks * 32);
            float4 p1 = *(const float4*)(inrow + ks * 32 + 4);
            float z[8] = {p0.x, p0.y, p0.z, p0.w, p1.x, p1.y, p1.z, p1.w};
            #pragma unroll
            for (int e = 0; e < 8; ++e) {
                unsigned short hu = bf16_of(z[e]);
                ah[ks][e] = (short)hu;
                al[ks][e] = (short)bf16_of(z[e] - f32_of(hu));
            }
        }

        f32x4 acc[8];
        #pragma unroll
        for (int ct = 0; ct < 8; ++ct) { f32x4 zz = {0.f, 0.f, 0.f, 0.f}; acc[ct] = zz; }

        #pragma unroll
        for (int ct = 0; ct < 8; ++ct) {
            #pragma unroll
            for (int ks = 0; ks < 4; ++ks) {
                const bf16x8 bh = *(const bf16x8*)(sWh + ((ks * 8 + ct) * 64 + l) * 8);
                const bf16x8 bl = *(const bf16x8*)(sWl + ((ks * 8 + ct) * 64 + l) * 8);
                acc[ct] = __builtin_amdgcn_mfma_f32_16x16x32_bf16(ah[ks], bh, acc[ct], 0, 0, 0);
                acc[ct] = __builtin_amdgcn_mfma_f32_16x16x32_bf16(ah[ks], bl, acc[ct], 0, 0, 0);
                acc[ct] = __builtin_amdgcn_mfma_f32_16x16x32_bf16(al[ks], bh, acc[ct], 0, 0, 0);
            }
        }

        #pragma unroll
        for (int j = 0; j < 4; ++j) {
            int m = row0 + w * 16 + lk * 4 + j;
            if (m < nrows) {
                #pragma unroll
                for (int ct = 0; ct < 8; ++ct)
                    outp[(size_t)m * 128 + ct * 16 + lr] = bf16_of(acc[ct][j]);
            }
        }
    }
}

// ===== shared agg helper pattern (ILP-4): 4 lanes of a row load 4 records at once,
// shfl-broadcast within the 16-stride lane group, then 4 independent row gathers. =====

// ================= FUSED agg + GEMM: out = bf16( relu(bias + norm-agg(raw)) @ W ) ======
__global__ __launch_bounds__(512) void k_fused_agg_gemm(
    const unsigned short* __restrict__ raw, const float* __restrict__ dinv,
    const int* __restrict__ off, const int4* __restrict__ csr_pack,
    const float* __restrict__ bias,
    const unsigned short* __restrict__ Whf, const unsigned short* __restrict__ Wlf,
    unsigned short* __restrict__ outp, int nrows)
{
    __shared__ __align__(16) unsigned short sWh[16384];
    __shared__ __align__(16) unsigned short sWl[16384];
    const int t = threadIdx.x;

    // issue weight staging first; agg gathers below overlap its latency
    #pragma unroll
    for (int i = 0; i < 4; ++i) {
        ((float4*)sWh)[t + 512 * i] = ((const float4*)Whf)[t + 512 * i];
        ((float4*)sWl)[t + 512 * i] = ((const float4*)Wlf)[t + 512 * i];
    }

    const int w = t >> 6, l = t & 63;
    const int lr = l & 15, lk = l >> 4;
    const int row0 = blockIdx.x * 128;
    int arow = row0 + w * 16 + lr;
    if (arow >= nrows) arow = nrows - 1;

    const unsigned short* self = raw + (size_t)arow * 128 + lk * 8;
    const float* brow = bias + lk * 8;
    float di = dinv[arow];
    float w0 = di * di;

    float facc[4][8];
    #pragma unroll
    for (int ks = 0; ks < 4; ++ks) {
        bf16x8 v = *(const bf16x8*)(self + ks * 32);
        float4 b0 = *(const float4*)(brow + ks * 32);
        float4 b1v = *(const float4*)(brow + ks * 32 + 4);
        float bb[8] = {b0.x, b0.y, b0.z, b0.w, b1v.x, b1v.y, b1v.z, b1v.w};
        #pragma unroll
        for (int e = 0; e < 8; ++e)
            facc[ks][e] = bb[e] + w0 * f32_of((unsigned short)v[e]);
    }

    const int beg = off[arow], end = off[arow + 1];
    for (int j = beg; j < end; j += 4) {
        int4 p = make_int4(0, 0, 0, 0);
        if (j + lk < end) p = csr_pack[j + lk];     // 4 records, one per lane
        #pragma unroll
        for (int k = 0; k < 4; ++k) {
            if (j + k < end) {                       // row-uniform predicate
                int si = __shfl(p.x, lr + 16 * k, 64);
                float wg = __int_as_float(__shfl(p.z, lr + 16 * k, 64));
                const unsigned short* nrow = raw + (size_t)si * 128 + lk * 8;
                #pragma unroll
                for (int ks = 0; ks < 4; ++ks) {
                    bf16x8 u = *(const bf16x8*)(nrow + ks * 32);
                    #pragma unroll
                    for (int e = 0; e < 8; ++e)
                        facc[ks][e] += wg * f32_of((unsigned short)u[e]);
                }
            }
        }
    }

    bf16x8 ah[4];
    #pragma unroll
    for (int ks = 0; ks < 4; ++ks)
        #pragma unroll
        for (int e = 0; e < 8; ++e)
            ah[ks][e] = (short)bf16_of(fmaxf(facc[ks][e], 0.f));

    __syncthreads();                                 // weights staged

    f32x4 acc[8];
    #pragma unroll
    for (int ct = 0; ct < 8; ++ct) { f32x4 zz = {0.f, 0.f, 0.f, 0.f}; acc[ct] = zz; }
    #pragma unroll
    for (int ct = 0; ct < 8; ++ct) {
        #pragma unroll
        for (int ks = 0; ks < 4; ++ks) {
            const bf16x8 bh = *(const bf16x8*)(sWh + ((ks * 8 + ct) * 64 + l) * 8);
            const bf16x8 bl = *(const bf16x8*)(sWl + ((ks * 8 + ct) * 64 + l) * 8);
            acc[ct] = __builtin_amdgcn_mfma_f32_16x16x32_bf16(ah[ks], bh, acc[ct], 0, 0, 0);
            acc[ct] = __builtin_amdgcn_mfma_f32_16x16x32_bf16(ah[ks], bl, acc[ct], 0, 0, 0);
        }
    }

    #pragma unroll
    for (int j = 0; j < 4; ++j) {
        int m = row0 + w * 16 + lk * 4 + j;
        if (m < nrows) {
            #pragma unroll
            for (int ct = 0; ct < 8; ++ct)
                outp[(size_t)m * 128 + ct * 16 + lr] = bf16_of(acc[ct][j]);
        }
    }
}

// ================= FUSED agg + P/Q GEMMs: z=relu(bias+agg); P=z@Wa + bm1; Q=z@Wb =======
__global__ __launch_bounds__(512) void k_fused_agg_pq(
    const unsigned short* __restrict__ raw, const float* __restrict__ dinv,
    const int* __restrict__ off, const int4* __restrict__ csr_pack,
    const float* __restrict__ bias, const float* __restrict__ bm1,
    const unsigned short* __restrict__ Wh0, const unsigned short* __restrict__ Wl0,
    const unsigned short* __restrict__ Wh1, const unsigned short* __restrict__ Wl1,
    unsigned short* __restrict__ P, unsigned short* __restrict__ Q, int nrows)
{
    __shared__ __align__(16) unsigned short sWh[16384];
    __shared__ __align__(16) unsigned short sWl[16384];
    const int t = threadIdx.x;

    #pragma unroll
    for (int i = 0; i < 4; ++i) {
        ((float4*)sWh)[t + 512 * i] = ((const float4*)Wh0)[t + 512 * i];
        ((float4*)sWl)[t + 512 * i] = ((const float4*)Wl0)[t + 512 * i];
    }

    const int w = t >> 6, l = t & 63;
    const int lr = l & 15, lk = l >> 4;
    const int row0 = blockIdx.x * 128;
    int arow = row0 + w * 16 + lr;
    if (arow >= nrows) arow = nrows - 1;

    const unsigned short* self = raw + (size_t)arow * 128 + lk * 8;
    const float* brow = bias + lk * 8;
    float di = dinv[arow];
    float w0 = di * di;

    float facc[4][8];
    #pragma unroll
    for (int ks = 0; ks < 4; ++ks) {
        bf16x8 v = *(const bf16x8*)(self + ks * 32);
        float4 b0 = *(const float4*)(brow + ks * 32);
        float4 b1v = *(const float4*)(brow + ks * 32 + 4);
        float bb[8] = {b0.x, b0.y, b0.z, b0.w, b1v.x, b1v.y, b1v.z, b1v.w};
        #pragma unroll
        for (int e = 0; e < 8; ++e)
            facc[ks][e] = bb[e] + w0 * f32_of((unsigned short)v[e]);
    }

    const int beg = off[arow], end = off[arow + 1];
    for (int j = beg; j < end; j += 4) {
        int4 p = make_int4(0, 0, 0, 0);
        if (j + lk < end) p = csr_pack[j + lk];
        #pragma unroll
        for (int k = 0; k < 4; ++k) {
            if (j + k < end) {
                int si = __shfl(p.x, lr + 16 * k, 64);
                float wg = __int_as_float(__shfl(p.z, lr + 16 * k, 64));
                const unsigned short* nrow = raw + (size_t)si * 128 + lk * 8;
                #pragma unroll
                for (int ks = 0; ks < 4; ++ks) {
                    bf16x8 u = *(const bf16x8*)(nrow + ks * 32);
                    #pragma unroll
                    for (int e = 0; e < 8; ++e)
                        facc[ks][e] += wg * f32_of((unsigned short)u[e]);
                }
            }
        }
    }

    bf16x8 ah[4];
    #pragma unroll
    for (int ks = 0; ks < 4; ++ks)
        #pragma unroll
        for (int e = 0; e < 8; ++e)
            ah[ks][e] = (short)bf16_of(fmaxf(facc[ks][e], 0.f));

    // bm1 folded into P: bmv[ct] = bm1[ct*16+lr]
    float bmv[8];
    #pragma unroll
    for (int ct = 0; ct < 8; ++ct) bmv[ct] = bm1[ct * 16 + lr];

    __syncthreads();                                 // W0 staged

    {
        f32x4 acc[8];
        #pragma unroll
        for (int ct = 0; ct < 8; ++ct) { f32x4 zz = {0.f, 0.f, 0.f, 0.f}; acc[ct] = zz; }
        #pragma unroll
        for (int ct = 0; ct < 8; ++ct) {
            #pragma unroll
            for (int ks = 0; ks < 4; ++ks) {
                const bf16x8 bh = *(const bf16x8*)(sWh + ((ks * 8 + ct) * 64 + l) * 8);
                const bf16x8 bl = *(const bf16x8*)(sWl + ((ks * 8 + ct) * 64 + l) * 8);
                acc[ct] = __builtin_amdgcn_mfma_f32_16x16x32_bf16(ah[ks], bh, acc[ct], 0, 0, 0);
                acc[ct] = __builtin_amdgcn_mfma_f32_16x16x32_bf16(ah[ks], bl, acc[ct], 0, 0, 0);
            }
        }
        #pragma unroll
        for (int j = 0; j < 4; ++j) {
            int m = row0 + w * 16 + lk * 4 + j;
            if (m < nrows) {
                #pragma unroll
                for (int ct = 0; ct < 8; ++ct)
                    P[(size_t)m * 128 + ct * 16 + lr] = bf16_of(acc[ct][j] + bmv[ct]);
            }
        }
    }

    __syncthreads();                                 // all reads of W0 done
    #pragma unroll
    for (int i = 0; i < 4; ++i) {
        ((float4*)sWh)[t + 512 * i] = ((const float4*)Wh1)[t + 512 * i];
        ((float4*)sWl)[t + 512 * i] = ((const float4*)Wl1)[t + 512 * i];
    }
    __syncthreads();                                 // W1 staged

    {
        f32x4 acc[8];
        #pragma unroll
        for (int ct = 0; ct < 8; ++ct) { f32x4 zz = {0.f, 0.f, 0.f, 0.f}; acc[ct] = zz; }
        #pragma unroll
        for (int ct = 0; ct < 8; ++ct) {
            #pragma unroll
            for (int ks = 0; ks < 4; ++ks) {
                const bf16x8 bh = *(const bf16x8*)(sWh + ((ks * 8 + ct) * 64 + l) * 8);
                const bf16x8 bl = *(const bf16x8*)(sWl + ((ks * 8 + ct) * 64 + l) * 8);
                acc[ct] = __builtin_amdgcn_mfma_f32_16x16x32_bf16(ah[ks], bh, acc[ct], 0, 0, 0);
                acc[ct] = __builtin_amdgcn_mfma_f32_16x16x32_bf16(ah[ks], bl, acc[ct], 0, 0, 0);
            }
        }
        #pragma unroll
        for (int j = 0; j < 4; ++j) {
            int m = row0 + w * 16 + lk * 4 + j;
            if (m < nrows) {
                #pragma unroll
                for (int ct = 0; ct < 8; ++ct)
                    Q[(size_t)m * 128 + ct * 16 + lr] = bf16_of(acc[ct][j]);
            }
        }
    }
}

// ================= fused edge MLP (MFMA 2-term, CSR order, phase-split weights) ========
// bm1 already folded into P -> z1 = relu(P[s] + Q[d]).
__global__ __launch_bounds__(512) void k_edge_mlp_mfma(
    const int4* __restrict__ csr_pack,
    const unsigned short* __restrict__ P, const unsigned short* __restrict__ Q,
    const unsigned short* __restrict__ Whf, const unsigned short* __restrict__ Wlf,
    const float* __restrict__ bm2,
    const float* __restrict__ Wm3, const float* __restrict__ bm3,
    float* __restrict__ outp)
{
    __shared__ __align__(16) unsigned short sW[16384];   // 32 KB: [0,8192)=h, [8192,16384)=l
    __shared__ int sIdx[3][128];

    const int t = threadIdx.x;
    const int e0 = blockIdx.x * 128;

    if (t < 128) {
        int4 p = csr_pack[e0 + t];
        sIdx[0][t] = p.x;
        sIdx[1][t] = p.y;
        sIdx[2][t] = p.w;
    }
    __syncthreads();

    const int w = t >> 6;          // wave id 0..7: rows w*16 .. w*16+15
    const int l = t & 63;
    const int lr = l & 15;         // A row within tile / D col
    const int lk = l >> 4;         // k-block
    const int row = w * 16 + lr;
    const int s = sIdx[0][row], d = sIdx[1][row];
    const unsigned short* prow = P + (size_t)s * 128 + lk * 8;
    const unsigned short* qrow = Q + (size_t)d * 128 + lk * 8;

    bf16x8 ah[4];
    #pragma unroll
    for (int ks = 0; ks < 4; ++ks) {
        bf16x8 pv = *(const bf16x8*)(prow + ks * 32);
        bf16x8 qv = *(const bf16x8*)(qrow + ks * 32);
        #pragma unroll
        for (int e = 0; e < 8; ++e) {
            float zv = fmaxf(f32_of((unsigned short)pv[e]) +
                             f32_of((unsigned short)qv[e]), 0.f);
            ah[ks][e] = (short)bf16_of(zv);
        }
    }

    f32x4 acc[8];
    #pragma unroll
    for (int ct = 0; ct < 8; ++ct) {
        float bv = bm2[ct * 16 + lr];
        f32x4 a = {bv, bv, bv, bv};
        acc[ct] = a;
    }

    // two phases: ct in [0,4) then [4,8); each stages 16 h-tiles + 16 l-tiles (32 KB)
    #pragma unroll
    for (int ph = 0; ph < 2; ++ph) {
        if (ph) __syncthreads();
        #pragma unroll
        for (int i = 0; i < 2; ++i) {
            int li = t + 512 * i;
            int tl = li >> 6, off = li & 63;
            int gtile = (tl >> 2) * 8 + ph * 4 + (tl & 3);
            ((float4*)sW)[li] = ((const float4*)Whf)[gtile * 64 + off];
            ((float4*)(sW + 8192))[li] = ((const float4*)Wlf)[gtile * 64 + off];
        }
        __syncthreads();
        #pragma unroll
        for (int ct4 = 0; ct4 < 4; ++ct4) {
            int ct = ph * 4 + ct4;
            #pragma unroll
            for (int ks = 0; ks < 4; ++ks) {
                int tl = ks * 4 + ct4;
                const bf16x8 bh = *(const bf16x8*)(sW + (tl * 64 + l) * 8);
                const bf16x8 bl = *(const bf16x8*)(sW + 8192 + (tl * 64 + l) * 8);
                acc[ct] = __builtin_amdgcn_mfma_f32_16x16x32_bf16(ah[ks], bh, acc[ct], 0, 0, 0);
                acc[ct] = __builtin_amdgcn_mfma_f32_16x16x32_bf16(ah[ks], bl, acc[ct], 0, 0, 0);
            }
        }
    }

    float w3v[8];
    #pragma unroll
    for (int ct = 0; ct < 8; ++ct) w3v[ct] = Wm3[ct * 16 + lr];
    float b3 = bm3[0];
    #pragma unroll
    for (int j = 0; j < 4; ++j) {
        float pj = 0.f;
        #pragma unroll
        for (int ct = 0; ct < 8; ++ct) pj += fmaxf(acc[ct][j], 0.f) * w3v[ct];
        pj += __shfl_xor(pj, 1);
        pj += __shfl_xor(pj, 2);
        pj += __shfl_xor(pj, 4);
        pj += __shfl_xor(pj, 8);
        if (lr == 0)
            outp[sIdx[2][w * 16 + lk * 4 + j]] = 1.f / (1.f + expf(-(pj + b3)));
    }
}

// ================= launch =================
extern "C" void kernel_launch(void* const* d_in, const int* in_sizes, int n_in,
                              void* d_out, int out_size, void* d_ws, size_t ws_size,
                              hipStream_t stream) {
    const float* x   = (const float*)d_in[0];
    const int*   ei  = (const int*)d_in[1];
    const float* W1  = (const float*)d_in[2];
    const float* b1  = (const float*)d_in[3];
    const float* W2  = (const float*)d_in[4];
    const float* b2  = (const float*)d_in[5];
    const float* Wm1 = (const float*)d_in[6];
    const float* bm1 = (const float*)d_in[7];
    const float* Wm2 = (const float*)d_in[8];
    const float* bm2 = (const float*)d_in[9];
    const float* Wm3 = (const float*)d_in[10];
    const float* bm3 = (const float*)d_in[11];
    const int* esrc = ei;
    const int* edst = ei + N_EDGES;
    float* outp = (float*)d_out;

    // workspace layout
    float* ws = (float*)d_ws;
    float* dinv = ws;                                   // 100096 floats
    float* A = ws + 100096;                             // N*128 f32 region
    float* B = A + (size_t)N_NODES * 128;               // N*128 f32 region
    int* deg     = (int*)(B + (size_t)N_NODES * 128);   // N
    int* off     = deg + N_NODES;                       // N+1
    int* cur     = off + N_NODES + 1;                   // N
    int* bsum    = cur + N_NODES;                       // 512
    // align to 16 B for int4
    size_t ioff = (size_t)(bsum + 512 - (int*)d_ws);
    ioff = (ioff + 3) & ~(size_t)3;
    int4* csr_pack = (int4*)((int*)d_ws + ioff);        // E int4
    unsigned short* frag = (unsigned short*)(csr_pack + N_EDGES);
    unsigned short* W1h   = frag;                 unsigned short* W1l   = frag + 16384;
    unsigned short* W2h   = frag + 2 * 16384;     unsigned short* W2l   = frag + 3 * 16384;
    unsigned short* Wm1ah = frag + 4 * 16384;     unsigned short* Wm1al = frag + 5 * 16384;
    unsigned short* Wm1bh = frag + 6 * 16384;     unsigned short* Wm1bl = frag + 7 * 16384;
    unsigned short* Wm2h  = frag + 8 * 16384;     unsigned short* Wm2l  = frag + 9 * 16384;
    // bf16 views: Ab = layer-1 product (region A); Cb = layer-2 product (region B);
    // Pb overwrites Ab (dead once fused_pq reads only Cb); Qb after Pb in region A.
    unsigned short* Ab = (unsigned short*)A;
    unsigned short* Cb = (unsigned short*)B;
    unsigned short* Pb = (unsigned short*)A;
    unsigned short* Qb = (unsigned short*)A + (size_t)N_NODES * 128;

    const int nb = (N_NODES + 255) / 256;               // 391 scan blocks

    // ---- CSR build + W splits ----
    k_zero_deg<<<nb, 256, 0, stream>>>(deg);
    k_hist<<<(N_EDGES + 255) / 256, 256, 0, stream>>>(edst, deg);
    k_scan1<<<nb, 256, 0, stream>>>(deg, off, bsum, dinv, N_NODES);
    k_scan2<<<1, 512, 0, stream>>>(bsum, nb);
    k_scan3<<<(N_NODES + 256) / 256, 256, 0, stream>>>(off, bsum, cur, N_NODES);
    k_scatter<<<(N_EDGES + 255) / 256, 256, 0, stream>>>(esrc, edst, dinv, cur, csr_pack);

    SplitArgs sa;
    sa.W[0] = W1;  sa.Wh[0] = W1h;   sa.Wl[0] = W1l;
    sa.W[1] = W2;  sa.Wh[1] = W2h;   sa.Wl[1] = W2l;
    sa.W[2] = Wm1; sa.Wh[2] = Wm1ah; sa.Wl[2] = Wm1al;
    sa.W[3] = Wm1 + 128 * 128; sa.Wh[3] = Wm1bh; sa.Wl[3] = Wm1bl;
    sa.W[4] = Wm2; sa.Wh[4] = Wm2h;  sa.Wl[4] = Wm2l;
    k_split_all<<<5 * 64, 256, 0, stream>>>(sa);

    const int RT = 4;
    const int gemm_blocks = (N_NODES + 128 * RT - 1) / (128 * RT);   // 196
    const int node_tiles = (N_NODES + 127) / 128;                    // 782

    // ---- layer 1 product: Ab = bf16(x @ W1) ----
    k_gemm_mfma_f32<<<gemm_blocks, 512, 0, stream>>>(x, W1h, W1l, Ab, N_NODES, RT);

    // ---- fused: Cb = bf16( relu(b1 + agg(Ab)) @ W2 ) ----
    k_fused_agg_gemm<<<node_tiles, 512, 0, stream>>>(Ab, dinv, off, csr_pack, b1,
                                                     W2h, W2l, Cb, N_NODES);

    // ---- fused: z2 = relu(b2 + agg(Cb)); Pb = z2@Wm1_top + bm1; Qb = z2@Wm1_bot ----
    k_fused_agg_pq<<<node_tiles, 512, 0, stream>>>(Cb, dinv, off, csr_pack, b2, bm1,
                                                   Wm1ah, Wm1al, Wm1bh, Wm1bl,
                                                   Pb, Qb, N_NODES);

    // ---- fused edge MLP on MFMA, CSR order, phase-split weight LDS ----
    k_edge_mlp_mfma<<<N_EDGES / 128, 512, 0, stream>>>(csr_pack, Pb, Qb,
                                                       Wm2h, Wm2l, bm2, Wm3, bm3, outp);
}